// Round 7
// baseline (66.436 us; speedup 1.0000x reference)
//
#include <hip/hip_runtime.h>
#include <hip/hip_bf16.h>

// Problem constants (from reference): B=32, N=2048, M=16, K=32, H=in_sizes[2]
constexpr int Bc = 32;
constexpr int Nc = 2048;
constexpr int Mc = 16;
constexpr int Kc = 32;
constexpr int ROWc = Mc + 1;       // 17 floats per dgm row
constexpr int HALF = 1024;         // rows per half-block; lengths >= N/2 = 1024
constexpr float EPSc = 1e-7f;
constexpr float HALF_LN2 = 0.34657359028f;   // 0.5 * ln(2)

// ---------------------------------------------------------------------------
// Kernel A: one block per (b, k, half), 2048 blocks x 256 threads.
// No LDS staging (dgm is L2-resident), no per-chunk barriers.
//   half 0: rows [0,1024) are guaranteed valid (lengths >= N/2) -> no
//           validity logic at all.
//   half 1: one cheap pre-pass finds the block-local first all-zero row
//           (= lengths[b]) with a single barrier, then compute.
// Math: v*w = 0.5*asinh(zn)/zn * z * wv  (atanh(||x||) = asinh(||z||)/2),
//   and z = y*th, so  P += coef*y  with  coef = 0.5*asinh(zn)/zn*wv, and the
//   th[m] factor is applied once at the epilogue. No divisions in the loop.
// Partial sums stored to P[bid][m] (d_ws); k_scan adds the two halves.
// ---------------------------------------------------------------------------
__global__ __launch_bounds__(256) void k_T(const float* __restrict__ dgm,
                                           const float* __restrict__ theta,
                                           const float* __restrict__ class_w,
                                           float* __restrict__ P,
                                           int H) {
    __shared__ int   wmin[4];
    __shared__ float red[4][Mc];

    int bid  = blockIdx.x;
    int half = bid & 1;
    int bk   = bid >> 1;
    int b    = bk >> 5;                // K = 32
    int k    = bk & 31;
    int tid  = threadIdx.x;
    int wid  = tid >> 6;

    const float* base = dgm + ((size_t)b * Nc + half * HALF) * ROWc;

    // th^2 for zn2 (th itself applied at epilogue); k uniform -> scalar loads
    float th2[Mc];
#pragma unroll
    for (int m = 0; m < Mc; ++m) {
        float t = theta[k * Mc + m];
        th2[m] = t * t;
    }

    // ---- validity: local row limit within this half ----
    int fzb = HALF;                    // half 0: everything valid
    if (half) {
        int lm = 0x7FFFFFFF;
        for (int it = 0; it < 4; ++it) {
            int n = tid + it * 256;
            const float* row = base + (size_t)n * ROWc;
            bool nz = false;
#pragma unroll
            for (int j = 0; j < ROWc; ++j) nz = nz || (row[j] != 0.0f);
            if (!nz) lm = min(lm, n);
        }
#pragma unroll
        for (int mask = 32; mask >= 1; mask >>= 1)
            lm = min(lm, __shfl_xor(lm, mask));
        if ((tid & 63) == 0) wmin[wid] = lm;
        __syncthreads();
        fzb = min(HALF, min(min(wmin[0], wmin[1]), min(wmin[2], wmin[3])));
    }

    // ---- accumulate 4 strided rows/thread, no barriers ----
    float acc[Mc];
#pragma unroll
    for (int m = 0; m < Mc; ++m) acc[m] = 0.0f;

    for (int it = 0; it < 4; ++it) {
        int n = tid + it * 256;
        if (n >= fzb) break;           // n monotone -> break ok
        const float* row = base + (size_t)n * ROWc;

        float r0 = row[0];
        float r[Mc];
#pragma unroll
        for (int m = 0; m < Mc; ++m) r[m] = row[1 + m];

        int h = (int)r0;               // trunc == astype(int32)
        h = max(0, min(h, H - 1));
        float wv = class_w[h];

        float zn2 = 0.0f;
#pragma unroll
        for (int m = 0; m < Mc; ++m) zn2 = fmaf(r[m] * r[m], th2[m], zn2);

        // coef = 0.5*asinh(zn)/zn * wv ; asinh(zn) = log(zn + sqrt(1+zn2))
        float s   = sqrtf(1.0f + zn2);
        float zn  = sqrtf(zn2);
        float at2 = __log2f(zn + s);                       // log2
        float coef = HALF_LN2 * at2 * rsqrtf(fmaxf(zn2, 1e-30f)) * wv;
        // zn2==0: at2=log2(1)=0 -> coef=0 (finite) -> correct zero contribution

#pragma unroll
        for (int m = 0; m < Mc; ++m) acc[m] = fmaf(coef, r[m], acc[m]);
    }

    // ---- block reduce: wave-64 shfl, then LDS across 4 waves ----
#pragma unroll
    for (int m = 0; m < Mc; ++m) {
#pragma unroll
        for (int mask = 32; mask >= 1; mask >>= 1)
            acc[m] += __shfl_xor(acc[m], mask);
    }
    __syncthreads();                   // half 1: wmin reads done; half 0: first barrier
    if ((tid & 63) == 0) {
#pragma unroll
        for (int m = 0; m < Mc; ++m) red[wid][m] = acc[m];
    }
    __syncthreads();
    if (tid < Mc) {
        float ssum = red[0][tid] + red[1][tid] + red[2][tid] + red[3][tid];
        P[(size_t)bid * Mc + tid] = ssum * theta[k * Mc + tid];
    }
}

// ---------------------------------------------------------------------------
// Kernel B: T[row][m] = P[2*row][m] + P[2*row+1][m]; S = cumsum over the
// 1024 flattened rows; yd = 2*xd/(1-||xd||^2), xd = tanh(||S||)*S/max(||S||,eps).
// Single block, 1024 threads. thread = (m = tid&15, seg = tid>>4).
// ---------------------------------------------------------------------------
__global__ __launch_bounds__(1024) void k_scan(const float* __restrict__ P,
                                               float* __restrict__ out) {
    __shared__ float buf[2][64][Mc];

    int tid = threadIdx.x;
    int m   = tid & 15;
    int seg = tid >> 4;            // 0..63, 16 rows each -> 1024 rows

    float p[16];
    float run = 0.0f;
#pragma unroll
    for (int j = 0; j < 16; ++j) {
        int row = seg * 16 + j;
        run += P[(size_t)(2 * row) * Mc + m] + P[(size_t)(2 * row + 1) * Mc + m];
        p[j] = run;
    }

    buf[0][seg][m] = run;
    __syncthreads();
    int src = 0;
#pragma unroll
    for (int d = 1; d < 64; d <<= 1) {
        float v = buf[src][seg][m];
        if (seg >= d) v += buf[src][seg - d][m];
        buf[src ^ 1][seg][m] = v;
        __syncthreads();
        src ^= 1;
    }
    float off = (seg > 0) ? buf[src][seg - 1][m] : 0.0f;

#pragma unroll
    for (int j = 0; j < 16; ++j) {
        float S = off + p[j];
        float sn2 = S * S;
        sn2 += __shfl_xor(sn2, 1);
        sn2 += __shfl_xor(sn2, 2);
        sn2 += __shfl_xor(sn2, 4);
        sn2 += __shfl_xor(sn2, 8);
        float sn = sqrtf(sn2);
        // tanh(sn) = 1 - 2/(e^{2 sn}+1)
        float e  = __expf(2.0f * sn);
        float t  = 1.0f - 2.0f / (e + 1.0f);
        float c  = t / fmaxf(sn, EPSc);
        float sx2 = c * c * sn2;               // == sum(xd^2)
        float yd = 2.0f * c * S / (1.0f - sx2);
        out[(size_t)(seg * 16 + j) * Mc + m] = yd;
    }
}

// ---------------------------------------------------------------------------
extern "C" void kernel_launch(void* const* d_in, const int* in_sizes, int n_in,
                              void* d_out, int out_size, void* d_ws, size_t ws_size,
                              hipStream_t stream) {
    const float* dgm     = (const float*)d_in[0];   // (B, N, 17)
    const float* theta   = (const float*)d_in[1];   // (K, M)
    const float* class_w = (const float*)d_in[2];   // (H,)
    int H = in_sizes[2];

    float* P   = (float*)d_ws;                      // 2048 x 16 partials (128 KB)
    float* out = (float*)d_out;

    k_T<<<Bc * Kc * 2, 256, 0, stream>>>(dgm, theta, class_w, P, H);
    k_scan<<<1, 1024, 0, stream>>>(P, out);
}

// Round 8
// 32.875 us; speedup vs baseline: 2.0209x; 2.0209x over previous
//
#include <hip/hip_runtime.h>
#include <hip/hip_bf16.h>

// Problem constants (from reference): B=32, N=2048, M=16, K=32, H=in_sizes[2]
constexpr int Bc = 32;
constexpr int Nc = 2048;
constexpr int Mc = 16;
constexpr int Kc = 32;
constexpr int ROWc = 17;           // 17 floats per dgm row
constexpr int CH = 256;            // rows per chunk
constexpr int NCH = Nc / CH;       // 8 chunks per batch
constexpr float EPSc = 1e-7f;
constexpr float HALF_LN2 = 0.34657359028f;   // 0.5 * ln 2

// ---------------------------------------------------------------------------
// Kernel A: one block per (b, chunk) = 256 blocks x 512 threads (8 waves).
// Thread (k = tid&31, rg = tid>>5) accumulates its k over 16 rows of the
// staged chunk. Rows staged ONCE per chunk and broadcast-read by all 32 k's
// (32x less staging than the (b,k)-block layout). No validity logic: zero
// rows contribute exactly 0 (zn2=0 -> log2(1)=0 -> coef=0), and the data's
// invalid rows are precisely the zero rows.
// Math: T[b,k,m] = th[k][m] * sum_n coef(n,k)*y[n,m],
//       coef = 0.5*asinh(zn)/zn * w   (atanh(||x||) = asinh(||z||)/2).
// Partials P[b][chunk][k][m] -> d_ws.
// ---------------------------------------------------------------------------
__global__ __launch_bounds__(512) void k_T(const float* __restrict__ dgm,
                                           const float* __restrict__ theta,
                                           const float* __restrict__ class_w,
                                           float* __restrict__ P,
                                           int H) {
    __shared__ float stage[CH * 20];   // [row][20]: hom at +0, coords at +4..+19
    __shared__ float red[8 * 544];     // [wave][k*17 + m], padded 17 -> no conflicts

    int bid = blockIdx.x;
    int b   = bid >> 3;                // 8 chunks per batch
    int c   = bid & 7;
    int tid = threadIdx.x;
    int k   = tid & 31;
    int rg  = tid >> 5;                // 16 rowgroups x 16 rows

    // ---- stage 256x17 floats (1088 float4, coalesced) into padded layout ----
    const float4* src4 = (const float4*)(dgm + ((size_t)b * Nc + c * CH) * ROWc);
    for (int i = tid; i < (CH * ROWc) / 4; i += 512) {
        float4 v = src4[i];
        unsigned g = 4u * i;
#pragma unroll
        for (int e = 0; e < 4; ++e) {
            unsigned ge  = g + e;
            unsigned row = ge / 17u;
            unsigned col = ge - row * 17u;
            float val = (e == 0) ? v.x : (e == 1) ? v.y : (e == 2) ? v.z : v.w;
            stage[row * 20 + (col == 0 ? 0u : col + 3u)] = val;
        }
    }

    // ---- per-thread theta^2 for its k (2 KB, L1/L2-hot) ----
    float th2[16];
    {
        const float4* t4 = (const float4*)theta;
#pragma unroll
        for (int q = 0; q < 4; ++q) {
            float4 tv = t4[k * 4 + q];
            th2[4*q+0] = tv.x * tv.x; th2[4*q+1] = tv.y * tv.y;
            th2[4*q+2] = tv.z * tv.z; th2[4*q+3] = tv.w * tv.w;
        }
    }
    float cw0 = class_w[0];
    float cw1 = (H > 1) ? class_w[1] : cw0;

    __syncthreads();

    // ---- accumulate 16 rows for this (k, rowgroup) ----
    float acc[16];
#pragma unroll
    for (int m = 0; m < 16; ++m) acc[m] = 0.0f;

#pragma unroll
    for (int j = 0; j < 16; ++j) {
        int row = rg * 16 + j;
        const float* rp = &stage[row * 20];
        float r0 = rp[0];
        float r[16];
        {   // aligned float4 LDS reads (broadcast across the 32 k-lanes)
            float4* rv = (float4*)r;
            const float4* lp = (const float4*)(rp + 4);
            rv[0] = lp[0]; rv[1] = lp[1]; rv[2] = lp[2]; rv[3] = lp[3];
        }

        int h = (int)r0;               // trunc == astype(int32)
        h = max(0, min(h, H - 1));
        float wv = (H == 2) ? (h ? cw1 : cw0) : class_w[h];

        float za = 0.f, zb = 0.f, zc = 0.f, zd = 0.f;   // 4 indep chains
#pragma unroll
        for (int m = 0; m < 16; m += 4) {
            za = fmaf(r[m]   * r[m],   th2[m],   za);
            zb = fmaf(r[m+1] * r[m+1], th2[m+1], zb);
            zc = fmaf(r[m+2] * r[m+2], th2[m+2], zc);
            zd = fmaf(r[m+3] * r[m+3], th2[m+3], zd);
        }
        float zn2 = (za + zb) + (zc + zd);
        float rs  = rsqrtf(fmaxf(zn2, 1e-30f));
        float zn  = zn2 * rs;                       // ||z|| (0 if zn2==0)
        float s   = sqrtf(1.0f + zn2);
        float at2 = __log2f(zn + s);                // log2(asinh arg)
        float coef = HALF_LN2 * at2 * rs * wv;      // exactly 0 for zero rows
#pragma unroll
        for (int m = 0; m < 16; ++m) acc[m] = fmaf(coef, r[m], acc[m]);
    }

    // ---- reduce 16 rowgroups: xor-32 pairs within wave, then LDS across 8 waves ----
#pragma unroll
    for (int m = 0; m < 16; ++m) acc[m] += __shfl_xor(acc[m], 32);

    int w = tid >> 6;
    if ((tid & 63) < 32) {
#pragma unroll
        for (int m = 0; m < 16; ++m) red[w * 544 + k * 17 + m] = acc[m];
    }
    __syncthreads();

    // ---- final: one (k,m) pair per thread; apply theta; store partial ----
    {
        int kk = tid >> 4;             // 0..31
        int mm = tid & 15;
        float s = 0.0f;
#pragma unroll
        for (int w2 = 0; w2 < 8; ++w2) s += red[w2 * 544 + kk * 17 + mm];
        P[(size_t)bid * 512 + tid] = s * theta[tid];   // theta[kk*16+mm] == theta[tid]
    }
}

// ---------------------------------------------------------------------------
// Kernel B: T[row][m] = sum_c P[b][c][k][m] (row = b*32+k); S = cumsum over
// the 1024 rows; yd = 2*xd/(1-||xd||^2), xd = tanh(||S||)*S/max(||S||,eps).
// Single block, 1024 threads. thread = (m = tid&15, seg = tid>>4).
// ---------------------------------------------------------------------------
__global__ __launch_bounds__(1024) void k_scan(const float* __restrict__ P,
                                               float* __restrict__ out) {
    __shared__ float buf[2][64][Mc];

    int tid = threadIdx.x;
    int m   = tid & 15;
    int seg = tid >> 4;            // 0..63, 16 rows each -> 1024 rows

    float p[16];
    float run = 0.0f;
#pragma unroll
    for (int j = 0; j < 16; ++j) {
        int row = seg * 16 + j;    // = b*32 + k
        int b   = row >> 5;
        int k   = row & 31;
        const float* q = P + (size_t)b * (NCH * 512) + k * 16 + m;
        float t0 = q[0]        + q[512]      + q[2 * 512] + q[3 * 512];
        float t1 = q[4 * 512]  + q[5 * 512]  + q[6 * 512] + q[7 * 512];
        run += t0 + t1;
        p[j] = run;
    }

    buf[0][seg][m] = run;
    __syncthreads();
    int src = 0;
#pragma unroll
    for (int d = 1; d < 64; d <<= 1) {
        float v = buf[src][seg][m];
        if (seg >= d) v += buf[src][seg - d][m];
        buf[src ^ 1][seg][m] = v;
        __syncthreads();
        src ^= 1;
    }
    float off = (seg > 0) ? buf[src][seg - 1][m] : 0.0f;

#pragma unroll
    for (int j = 0; j < 16; ++j) {
        float S = off + p[j];
        float sn2 = S * S;
        sn2 += __shfl_xor(sn2, 1);
        sn2 += __shfl_xor(sn2, 2);
        sn2 += __shfl_xor(sn2, 4);
        sn2 += __shfl_xor(sn2, 8);
        float sn = sqrtf(sn2);
        // tanh(sn) = 1 - 2/(e^{2 sn}+1)
        float e  = __expf(2.0f * sn);
        float t  = 1.0f - 2.0f / (e + 1.0f);
        float cc = t / fmaxf(sn, EPSc);
        float sx2 = cc * cc * sn2;             // == sum(xd^2)
        float yd = 2.0f * cc * S / (1.0f - sx2);
        out[(size_t)(seg * 16 + j) * Mc + m] = yd;
    }
}

// ---------------------------------------------------------------------------
extern "C" void kernel_launch(void* const* d_in, const int* in_sizes, int n_in,
                              void* d_out, int out_size, void* d_ws, size_t ws_size,
                              hipStream_t stream) {
    const float* dgm     = (const float*)d_in[0];   // (B, N, 17)
    const float* theta   = (const float*)d_in[1];   // (K, M)
    const float* class_w = (const float*)d_in[2];   // (H,)
    int H = in_sizes[2];

    float* P   = (float*)d_ws;                      // 256 x 512 floats = 512 KB
    float* out = (float*)d_out;

    k_T<<<Bc * NCH, 512, 0, stream>>>(dgm, theta, class_w, P, H);
    k_scan<<<1, 1024, 0, stream>>>(P, out);
}